// Round 10
// baseline (117.554 us; speedup 1.0000x reference)
//
#include <hip/hip_runtime.h>
#include <hip/hip_cooperative_groups.h>
#include <math.h>

namespace cg = cooperative_groups;

#define NB    8
#define NPTS  4096
#define NTH   1024
#define SPT   4
#define NFILT 16
#define MAXQ  512
#define MAXU  256
#define MAXK  256

// d_ws layout (~1.3 MB; no initialization required)
#define WS_PCC  0         // u32[8][16] pred active count per 256-chunk
#define WS_TCC  512       // u32[8][16] targ active count per 256-chunk
#define WS_PKEY 1024      // u64[8][4096] pred keys (chunk-local compaction)
#define WS_PPOS 263168    // float4[8][4096] pred pos (normalized) + idx in .w
#define WS_TPOS 787456    // float4[8][4096] targ pos (real) + idx in .w

__device__ __forceinline__ int blockReduceSumI(int v, int* scr, int tid) {
    #pragma unroll
    for (int o = 32; o > 0; o >>= 1) v += __shfl_down(v, o, 64);
    if ((tid & 63) == 0) scr[tid >> 6] = v;
    __syncthreads();
    if (tid == 0) {
        int s = 0;
        #pragma unroll
        for (int w = 0; w < NTH / 64; ++w) s += scr[w];
        scr[16] = s;
    }
    __syncthreads();
    return scr[16];
}

__device__ __forceinline__ float blockReduceSumF(float v, float* scr, int tid) {
    #pragma unroll
    for (int o = 32; o > 0; o >>= 1) v += __shfl_down(v, o, 64);
    if ((tid & 63) == 0) scr[tid >> 6] = v;
    __syncthreads();
    if (tid == 0) {
        float s = 0.0f;
        #pragma unroll
        for (int w = 0; w < NTH / 64; ++w) s += scr[w];
        scr[16] = s;
    }
    __syncthreads();
    return scr[16];
}

__device__ __forceinline__ float rowAngleDeg(float a0, float a1, float a2,
                                             float b0, float b1, float b2) {
    float dot = a0 * b0 + a1 * b1 + a2 * b2;
    float na = sqrtf(a0 * a0 + a1 * a1 + a2 * a2);
    float nb = sqrtf(b0 * b0 + b1 * b1 + b2 * b2);
    float c = dot / (na * nb);
    c = fminf(1.0f, fmaxf(-1.0f, c));
    return acosf(c) * 57.29577951308232f;  // /pi*180
}

// Single cooperative kernel: 64 blocks x 1024 threads.
// Phase 1 (all blocks): one thread per (tensor,batch,point); chunk-local
//   compaction into ws (ballot-prefix, zero global atomics, plain stores).
// grid.sync() (device-scope fence -> cross-XCD visibility).
// Phase 2 (blocks 0-7): sort-free NMS + matching per batch, as R9.
__global__ __launch_bounds__(NTH) void fused_kernel(const float* __restrict__ pred,
                                                    const float* __restrict__ targ,
                                                    unsigned char* __restrict__ ws,
                                                    float* __restrict__ out) {
    __shared__ int   wcnt16[16];
    __shared__ int   scr_i[32];
    __shared__ float scr_f[32];
    __shared__ int   cnt[4];
    __shared__ int   ccP[16], ccT[16];
    __shared__ unsigned long long f_key[NFILT];
    __shared__ float f_x[NFILT], f_y[NFILT], f_z[NFILT];
    __shared__ unsigned long long q_key[MAXQ];
    __shared__ float q_x[MAXQ], q_y[MAXQ], q_z[MAXQ];
    __shared__ int   q_res[MAXQ];
    __shared__ unsigned long long u_key[MAXU];
    __shared__ float u_x[MAXU], u_y[MAXU], u_z[MAXU];
    __shared__ float k_x[MAXK], k_y[MAXK], k_z[MAXK];
    __shared__ int   k_idx[MAXK];
    __shared__ unsigned int k_match[MAXK];

    const int blk = blockIdx.x;
    const int tid = threadIdx.x;

    // ================= phase 1: compaction =================
    {
        const int tensor = blk >> 5;              // 0..31 pred, 32..63 targ
        const int batch = (blk >> 2) & 7;
        const int n = (blk & 3) * 1024 + tid;
        const float* base = (tensor ? targ : pred)
                            + (size_t)batch * NPTS * 10 + (size_t)n * 10;
        float2 f0 = *(const float2*)base;         // conf_raw, off_z
        float2 f1 = *(const float2*)(base + 2);   // off_x, off_y
        float gz = (float)(n >> 10);
        float gx = (float)((n >> 5) & 31);
        float gy = (float)(n & 31);

        bool active;
        unsigned long long key = 0;
        float4 rec;
        if (tensor == 0) {
            float conf = 1.0f / (1.0f + expf(-f0.x));   // jax.nn.sigmoid
            active = conf > 0.5f;
            unsigned int u = ~(__float_as_uint(conf) | 0x80000000u);  // conf desc
            key = ((unsigned long long)u << 32) | (unsigned int)n;    // idx asc
            rec = make_float4((f0.y + gz) * 0.25f,
                              (f1.x + gx) * 0.03125f,
                              (f1.y + gy) * 0.03125f,
                              (float)n);
        } else {
            active = f0.x > 0.5f;
            rec = make_float4((f0.y + gz) * 0.25f * 25.0f,
                              (f1.x + gx) * 0.03125f * 25.0f,
                              (f1.y + gy) * 0.03125f * 4.0f,
                              (float)n);
        }

        const int lane = tid & 63, wv = tid >> 6;     // wave in [0,16)
        unsigned long long ball = __ballot(active);
        int lofs = __popcll(ball & ((1ull << lane) - 1ull));
        if (lane == 0) wcnt16[wv] = __popcll(ball);
        __syncthreads();
        const int group = tid >> 8;                   // 256-chunk within block
        int wb = 0;
        for (int w = group * 4; w < wv; ++w) wb += wcnt16[w];
        const int chunk256 = (blk & 3) * 4 + group;
        if ((tid & 255) == 0) {
            int t = wcnt16[group * 4] + wcnt16[group * 4 + 1]
                  + wcnt16[group * 4 + 2] + wcnt16[group * 4 + 3];
            ((unsigned int*)(ws + (tensor ? WS_TCC : WS_PCC)))[batch * 16 + chunk256]
                = (unsigned int)t;
        }
        if (active) {
            int e = batch * NPTS + chunk256 * 256 + wb + lofs;
            if (tensor == 0) {
                ((unsigned long long*)(ws + WS_PKEY))[e] = key;
                ((float4*)(ws + WS_PPOS))[e] = rec;
            } else {
                ((float4*)(ws + WS_TPOS))[e] = rec;
            }
        }
    }
    __threadfence();
    cg::this_grid().sync();
    if (blk >= NB) return;

    // ================= phase 2: NMS + matching =================
    const int b = blk;
    const float* pb = pred + (size_t)b * NPTS * 10;
    const float* tb = targ + (size_t)b * NPTS * 10;
    const unsigned long long* pkey = (const unsigned long long*)(ws + WS_PKEY) + b * NPTS;
    const float4* ppos = (const float4*)(ws + WS_PPOS) + b * NPTS;
    const float4* tpos = (const float4*)(ws + WS_TPOS) + b * NPTS;

    if (tid < 16) ccP[tid] = (int)((const unsigned int*)(ws + WS_PCC))[b * 16 + tid];
    else if (tid < 32) ccT[tid - 16] = (int)((const unsigned int*)(ws + WS_TCC))[b * 16 + tid - 16];
    __syncthreads();
    int np = 0, nt = 0;
    #pragma unroll
    for (int i = 0; i < 16; ++i) { np += ccP[i]; nt += ccT[i]; }

    // ---- load compacted records into registers (chunk-local gating) ----
    unsigned long long key[SPT];
    bool  act[SPT];
    int   pidx[SPT];
    float cx[SPT], cy[SPT], cz[SPT];
    #pragma unroll
    for (int s = 0; s < SPT; ++s) {
        int slot = tid + NTH * s;
        bool a = (slot & 255) < ccP[slot >> 8];
        act[s] = a;
        key[s] = ~0ull;
        cx[s] = cy[s] = cz[s] = 0.f; pidx[s] = 0;
        if (a) {
            key[s] = pkey[slot];
            float4 p = ppos[slot];
            cx[s] = p.x; cy[s] = p.y; cz[s] = p.z; pidx[s] = (int)p.w;
        }
    }
    bool  t_act[SPT];
    int   t_n[SPT];
    float t_x[SPT], t_y[SPT], t_z[SPT];
    #pragma unroll
    for (int s = 0; s < SPT; ++s) {
        int slot = tid + NTH * s;
        bool a = (slot & 255) < ccT[slot >> 8];
        t_act[s] = a;
        t_x[s] = t_y[s] = t_z[s] = 0.f; t_n[s] = 0;
        if (a) {
            float4 p = tpos[slot];
            t_x[s] = p.x; t_y[s] = p.y; t_z[s] = p.z; t_n[s] = (int)p.w;
        }
    }

    // ---- NMS fixpoint (exact reference trajectory, order via keys) ----
    int cur = np;
    int prev = -1;
    while (cur != prev) {
        // filter = per-wave confidence champion (min key among actives)
        {
            unsigned long long bk = ~0ull;
            float bx = 0.f, by = 0.f, bz = 0.f;
            #pragma unroll
            for (int s = 0; s < SPT; ++s)
                if (act[s] && key[s] < bk) { bk = key[s]; bx = cx[s]; by = cy[s]; bz = cz[s]; }
            #pragma unroll
            for (int o = 32; o > 0; o >>= 1) {
                unsigned long long ok = __shfl_xor(bk, o, 64);
                float ox = __shfl_xor(bx, o, 64);
                float oy = __shfl_xor(by, o, 64);
                float oz = __shfl_xor(bz, o, 64);
                if (ok < bk) { bk = ok; bx = ox; by = oy; bz = oz; }
            }
            if ((tid & 63) == 0) {
                int w = tid >> 6;
                f_key[w] = bk; f_x[w] = bx; f_y[w] = by; f_z[w] = bz;
            }
        }
        __syncthreads();

        // pass 1: s[j] = exists active i (key_i<key_j) within cutoff
        bool sflag[SPT], pend[SPT];
        #pragma unroll
        for (int s = 0; s < SPT; ++s) {
            sflag[s] = false; pend[s] = false;
            if (!act[s]) continue;
            bool found = false;
            for (int f = 0; f < NFILT; ++f) {
                if (f_key[f] < key[s]) {
                    float dx = f_x[f] - cx[s], dy = f_y[f] - cy[s], dz = f_z[f] - cz[s];
                    if (dx * dx + dy * dy + dz * dz < 4.0f) { found = true; break; }
                }
            }
            if (found) sflag[s] = true;
            else pend[s] = true;
        }
        // single-shot cooperative resolve (loops only on overflow)
        do {
            if (tid == 0) cnt[1] = 0;
            __syncthreads();   // fences prior q_* reads vs rewrites
            int qe[SPT];
            #pragma unroll
            for (int s = 0; s < SPT; ++s) {
                qe[s] = -1;
                if (pend[s]) {
                    int e = atomicAdd(&cnt[1], 1);
                    if (e < MAXQ) {
                        q_key[e] = key[s]; q_x[e] = cx[s]; q_y[e] = cy[s]; q_z[e] = cz[s];
                        q_res[e] = 0;
                        qe[s] = e; pend[s] = false;
                    }
                }
            }
            __syncthreads();
            const int Q = min(cnt[1], MAXQ);
            for (int e = 0; e < Q; ++e) {     // uniform loop
                unsigned long long qk = q_key[e];
                float qx = q_x[e], qy = q_y[e], qz = q_z[e];
                bool hit = false;
                #pragma unroll
                for (int s = 0; s < SPT; ++s) {
                    if (act[s] && key[s] < qk) {
                        float dx = cx[s] - qx, dy = cy[s] - qy, dz = cz[s] - qz;
                        if (dx * dx + dy * dy + dz * dz < 4.0f) hit = true;
                    }
                }
                if (hit) q_res[e] = 1;        // benign race: all writers store 1
            }
            __syncthreads();
            #pragma unroll
            for (int s = 0; s < SPT; ++s)
                if (qe[s] >= 0) sflag[s] = (q_res[qe[s]] != 0);
        } while (cnt[1] > MAXQ);

        // pass 2: supp[j] = exists u in U={active,!s} with key_u<key_j, d<cutoff
        bool upend[SPT], supp[SPT];
        #pragma unroll
        for (int s = 0; s < SPT; ++s) {
            upend[s] = act[s] && !sflag[s];
            supp[s] = false;
        }
        do {
            if (tid == 0) cnt[2] = 0;
            __syncthreads();   // fences prior u_* reads vs rewrites
            #pragma unroll
            for (int s = 0; s < SPT; ++s) {
                if (upend[s]) {
                    int e = atomicAdd(&cnt[2], 1);
                    if (e < MAXU) {
                        u_key[e] = key[s]; u_x[e] = cx[s]; u_y[e] = cy[s]; u_z[e] = cz[s];
                        upend[s] = false;
                    }
                }
            }
            __syncthreads();
            const int Ku = min(cnt[2], MAXU);
            #pragma unroll
            for (int s = 0; s < SPT; ++s) {
                if (!act[s] || supp[s]) continue;
                for (int e = 0; e < Ku; ++e) {
                    if (u_key[e] < key[s]) {
                        float dx = u_x[e] - cx[s], dy = u_y[e] - cy[s], dz = u_z[e] - cz[s];
                        if (dx * dx + dy * dy + dz * dz < 4.0f) { supp[s] = true; break; }
                    }
                }
            }
        } while (cnt[2] > MAXU);
        // commit
        int loc = 0;
        #pragma unroll
        for (int s = 0; s < SPT; ++s) {
            if (act[s] && supp[s]) act[s] = false;
            loc += act[s] ? 1 : 0;
        }
        prev = cur;
        cur = blockReduceSumI(loc, scr_i, tid);
    }
    const int n_pd = cur;

    // ---- matching: kept preds vs all targets, lowest target idx wins ----
    bool kpend[SPT];
    #pragma unroll
    for (int s = 0; s < SPT; ++s) kpend[s] = act[s];
    int loc_tp = 0;
    float loc_ang = 0.0f;
    do {
        if (tid == 0) cnt[3] = 0;
        __syncthreads();   // fences prior k_* reads vs rewrites
        #pragma unroll
        for (int s = 0; s < SPT; ++s) {
            if (kpend[s]) {
                int e = atomicAdd(&cnt[3], 1);
                if (e < MAXK) {
                    k_x[e] = cx[s] * 25.0f; k_y[e] = cy[s] * 25.0f; k_z[e] = cz[s] * 4.0f;
                    k_idx[e] = pidx[s];
                    k_match[e] = 0xFFFFFFFFu;
                    kpend[s] = false;
                }
            }
        }
        __syncthreads();
        const int K = min(cnt[3], MAXK);
        #pragma unroll
        for (int s = 0; s < SPT; ++s) {
            if (!t_act[s]) continue;
            float tx = t_x[s], ty = t_y[s], tz = t_z[s];
            for (int e = 0; e < K; ++e) {
                float dx = tx - k_x[e], dy = ty - k_y[e], dz = tz - k_z[e];
                if (dx * dx + dy * dy + dz * dz < 4.0f)
                    atomicMin(&k_match[e], (unsigned int)t_n[s]);  // few hits
            }
        }
        __syncthreads();
        if (tid < K) {
            unsigned int m = k_match[tid];
            if (m != 0xFFFFFFFFu) {
                ++loc_tp;
                const float2* pr = (const float2*)(pb + (size_t)k_idx[tid] * 10 + 4);
                float2 p0 = pr[0], p1 = pr[1], p2v = pr[2];
                float ax0 = p0.x, ax1 = p0.y, ax2 = p1.x;
                float ay0 = p1.y, ay1 = p2v.x, ay2 = p2v.y;
                float az0 = ax1 * ay2 - ax2 * ay1;
                float az1 = ax2 * ay0 - ax0 * ay2;
                float az2 = ax0 * ay1 - ax1 * ay0;
                const float2* tr = (const float2*)(tb + (size_t)m * 10 + 4);
                float2 t0 = tr[0], t1 = tr[1], t2v = tr[2];
                float bx0 = t0.x, bx1 = t0.y, bx2 = t1.x;
                float by0 = t1.y, by1 = t2v.x, by2 = t2v.y;
                float bz0 = bx1 * by2 - bx2 * by1;
                float bz1 = bx2 * by0 - bx0 * by2;
                float bz2 = bx0 * by1 - bx1 * by0;
                loc_ang += rowAngleDeg(ax0, ax1, ax2, bx0, bx1, bx2);
                loc_ang += rowAngleDeg(ay0, ay1, ay2, by0, by1, by2);
                loc_ang += rowAngleDeg(az0, az1, az2, bz0, bz1, bz2);
            }
        }
    } while (cnt[3] > MAXK);

    int tp = blockReduceSumI(loc_tp, scr_i, tid);
    float angsum = blockReduceSumF(loc_ang, scr_f, tid);

    if (tid == 0) {
        out[b * 3 + 0] = (float)tp;
        out[b * 3 + 1] = (float)(n_pd - tp);
        out[b * 3 + 2] = (float)(nt - tp);
        out[NB * 3 + b] = (tp > 0) ? (angsum / (3.0f * (float)tp)) : 0.0f;
    }
}

extern "C" void kernel_launch(void* const* d_in, const int* in_sizes, int n_in,
                              void* d_out, int out_size, void* d_ws, size_t ws_size,
                              hipStream_t stream) {
    const float* pred = (const float*)d_in[0];
    const float* targ = (const float*)d_in[1];
    float* out = (float*)d_out;
    unsigned char* ws = (unsigned char*)d_ws;
    void* args[] = {(void*)&pred, (void*)&targ, (void*)&ws, (void*)&out};
    hipLaunchCooperativeKernel((const void*)fused_kernel, dim3(64), dim3(NTH),
                               args, 0, stream);
}

// Round 11
// 80.569 us; speedup vs baseline: 1.4590x; 1.4590x over previous
//
#include <hip/hip_runtime.h>
#include <math.h>

#define NB    8
#define NPTS  4096
#define NTH   512         // 8 waves -> cheaper barriers
#define SPT   8
#define NWAVE (NTH / 64)
#define NFILT NWAVE
#define MAXQ  512
#define MAXU  256
#define MAXK  256

// d_ws layout (~1.6 MB; no initialization required)
#define WS_PCC  0         // u32[8][16] pred active count per 256-chunk
#define WS_TCC  512       // u32[8][16] targ active count per 256-chunk
#define WS_PREC 1024      // ulonglong2[8][4096][2]: packed pred records (32 B)
#define WS_TPOS 1049600   // float4[8][4096] targ pos (real) + idx in .w

__device__ __forceinline__ int blockReduceSumI(int v, int* scr, int tid) {
    #pragma unroll
    for (int o = 32; o > 0; o >>= 1) v += __shfl_down(v, o, 64);
    if ((tid & 63) == 0) scr[tid >> 6] = v;
    __syncthreads();
    if (tid == 0) {
        int s = 0;
        #pragma unroll
        for (int w = 0; w < NWAVE; ++w) s += scr[w];
        scr[16] = s;
    }
    __syncthreads();
    return scr[16];
}

__device__ __forceinline__ float rowAngleDeg(float a0, float a1, float a2,
                                             float b0, float b1, float b2) {
    float dot = a0 * b0 + a1 * b1 + a2 * b2;
    float na = sqrtf(a0 * a0 + a1 * a1 + a2 * a2);
    float nb = sqrtf(b0 * b0 + b1 * b1 + b2 * b2);
    float c = dot / (na * nb);
    c = fminf(1.0f, fmaxf(-1.0f, c));
    return acosf(c) * 57.29577951308232f;  // /pi*180
}

// Prep: full-chip parallel load + chunk-local compaction. 256 blocks x 256.
// Zero global atomics; each block owns one (tensor,batch,chunk) and writes
// its count with a plain store. Pred records packed to one 32-B struct.
__global__ __launch_bounds__(256) void prep_kernel(const float* __restrict__ pred,
                                                   const float* __restrict__ targ,
                                                   unsigned char* __restrict__ ws) {
    __shared__ int wcnt[4];
    unsigned int* pcc = (unsigned int*)(ws + WS_PCC);
    unsigned int* tcc = (unsigned int*)(ws + WS_TCC);
    ulonglong2* prec = (ulonglong2*)(ws + WS_PREC);
    float4* tpos = (float4*)(ws + WS_TPOS);

    const int tid = threadIdx.x;
    const int blk = blockIdx.x;
    const int tensor = blk >> 7;            // 0 = pred, 1 = targ
    const int batch = (blk >> 4) & 7;
    const int chunk = blk & 15;
    const int n = chunk * 256 + tid;
    const float* base = (tensor ? targ : pred)
                        + (size_t)batch * NPTS * 10 + (size_t)n * 10;
    float2 f0 = *(const float2*)base;         // conf_raw, off_z
    float2 f1 = *(const float2*)(base + 2);   // off_x, off_y
    float gz = (float)(n >> 10);
    float gx = (float)((n >> 5) & 31);
    float gy = (float)(n & 31);

    bool active;
    unsigned long long key = 0;
    float rx, ry, rz;
    if (tensor == 0) {
        float conf = 1.0f / (1.0f + expf(-f0.x));   // jax.nn.sigmoid
        active = conf > 0.5f;
        unsigned int u = ~(__float_as_uint(conf) | 0x80000000u);  // conf desc
        key = ((unsigned long long)u << 32) | (unsigned int)n;    // idx asc
        rx = (f0.y + gz) * 0.25f;
        ry = (f1.x + gx) * 0.03125f;
        rz = (f1.y + gy) * 0.03125f;
    } else {
        active = f0.x > 0.5f;
        rx = (f0.y + gz) * 0.25f * 25.0f;
        ry = (f1.x + gx) * 0.03125f * 25.0f;
        rz = (f1.y + gy) * 0.03125f * 4.0f;
    }

    const int lane = tid & 63, wid = tid >> 6;
    unsigned long long ball = __ballot(active);
    int lofs = __popcll(ball & ((1ull << lane) - 1ull));
    if (lane == 0) wcnt[wid] = __popcll(ball);
    __syncthreads();
    int wb = 0;
    for (int w = 0; w < wid; ++w) wb += wcnt[w];
    if (tid == 0) {
        unsigned int t = (unsigned int)(wcnt[0] + wcnt[1] + wcnt[2] + wcnt[3]);
        (tensor ? tcc : pcc)[batch * 16 + chunk] = t;
    }
    if (active) {
        int e = batch * NPTS + chunk * 256 + wb + lofs;
        if (tensor == 0) {
            unsigned long long xy = ((unsigned long long)__float_as_uint(ry) << 32)
                                    | __float_as_uint(rx);
            unsigned long long zn = ((unsigned long long)(unsigned int)n << 32)
                                    | __float_as_uint(rz);
            prec[2 * e]     = make_ulonglong2(key, xy);
            prec[2 * e + 1] = make_ulonglong2(zn, 0ull);
        } else {
            tpos[e] = make_float4(rx, ry, rz, (float)n);
        }
    }
}

// Main: one block per batch (512 thr), compacted records only. Sort-free NMS
// (order via u64 keys); single-shot chunk loops with overflow fallback;
// benign-race LDS result stores.
__global__ __launch_bounds__(NTH) void molan_kernel(const float* __restrict__ pred,
                                                    const float* __restrict__ targ,
                                                    const unsigned char* __restrict__ ws,
                                                    float* __restrict__ out) {
    __shared__ int   scr_i[32];
    __shared__ float scr_f[32];
    __shared__ int   cnt[4];
    __shared__ int   ccP[16], ccT[16];
    __shared__ unsigned long long f_key[NFILT];
    __shared__ float f_x[NFILT], f_y[NFILT], f_z[NFILT];
    __shared__ unsigned long long q_key[MAXQ];
    __shared__ float q_x[MAXQ], q_y[MAXQ], q_z[MAXQ];
    __shared__ int   q_res[MAXQ];
    __shared__ unsigned long long u_key[MAXU];
    __shared__ float u_x[MAXU], u_y[MAXU], u_z[MAXU];
    __shared__ float k_x[MAXK], k_y[MAXK], k_z[MAXK];
    __shared__ int   k_idx[MAXK];
    __shared__ unsigned int k_match[MAXK];

    const int b = blockIdx.x;
    const int tid = threadIdx.x;
    const float* pb = pred + (size_t)b * NPTS * 10;
    const float* tb = targ + (size_t)b * NPTS * 10;
    const ulonglong2* prec = (const ulonglong2*)(ws + WS_PREC) + (size_t)b * NPTS * 2;
    const float4* tpos = (const float4*)(ws + WS_TPOS) + b * NPTS;

    if (tid < 16) ccP[tid] = (int)((const unsigned int*)(ws + WS_PCC))[b * 16 + tid];
    else if (tid < 32) ccT[tid - 16] = (int)((const unsigned int*)(ws + WS_TCC))[b * 16 + tid - 16];
    __syncthreads();
    int np = 0, nt = 0;
    #pragma unroll
    for (int i = 0; i < 16; ++i) { np += ccP[i]; nt += ccT[i]; }

    // ---- load compacted records into registers (chunk-local gating) ----
    unsigned long long key[SPT];
    bool  act[SPT];
    int   pidx[SPT];
    float cx[SPT], cy[SPT], cz[SPT];
    #pragma unroll
    for (int s = 0; s < SPT; ++s) {
        int slot = tid + NTH * s;
        bool a = (slot & 255) < ccP[slot >> 8];
        act[s] = a;
        key[s] = ~0ull;
        cx[s] = cy[s] = cz[s] = 0.f; pidx[s] = 0;
        if (a) {
            ulonglong2 w0 = prec[2 * slot];
            ulonglong2 w1 = prec[2 * slot + 1];
            key[s] = w0.x;
            cx[s] = __uint_as_float((unsigned int)w0.y);
            cy[s] = __uint_as_float((unsigned int)(w0.y >> 32));
            cz[s] = __uint_as_float((unsigned int)w1.x);
            pidx[s] = (int)(w1.x >> 32);
        }
    }
    bool  t_act[SPT];
    int   t_n[SPT];
    float t_x[SPT], t_y[SPT], t_z[SPT];
    #pragma unroll
    for (int s = 0; s < SPT; ++s) {
        int slot = tid + NTH * s;
        bool a = (slot & 255) < ccT[slot >> 8];
        t_act[s] = a;
        t_x[s] = t_y[s] = t_z[s] = 0.f; t_n[s] = 0;
        if (a) {
            float4 p = tpos[slot];
            t_x[s] = p.x; t_y[s] = p.y; t_z[s] = p.z; t_n[s] = (int)p.w;
        }
    }

    // ---- NMS fixpoint (exact reference trajectory, order via keys) ----
    int cur = np;
    int prev = -1;
    while (cur != prev) {
        // filter = per-wave confidence champion (min key among actives)
        {
            unsigned long long bk = ~0ull;
            float bx = 0.f, by = 0.f, bz = 0.f;
            #pragma unroll
            for (int s = 0; s < SPT; ++s)
                if (act[s] && key[s] < bk) { bk = key[s]; bx = cx[s]; by = cy[s]; bz = cz[s]; }
            #pragma unroll
            for (int o = 32; o > 0; o >>= 1) {
                unsigned long long ok = __shfl_xor(bk, o, 64);
                float ox = __shfl_xor(bx, o, 64);
                float oy = __shfl_xor(by, o, 64);
                float oz = __shfl_xor(bz, o, 64);
                if (ok < bk) { bk = ok; bx = ox; by = oy; bz = oz; }
            }
            if ((tid & 63) == 0) {
                int w = tid >> 6;
                f_key[w] = bk; f_x[w] = bx; f_y[w] = by; f_z[w] = bz;
            }
        }
        __syncthreads();

        // pass 1: s[j] = exists active i (key_i<key_j) within cutoff
        bool sflag[SPT], pend[SPT];
        #pragma unroll
        for (int s = 0; s < SPT; ++s) {
            sflag[s] = false; pend[s] = false;
            if (!act[s]) continue;
            bool found = false;
            for (int f = 0; f < NFILT; ++f) {
                if (f_key[f] < key[s]) {
                    float dx = f_x[f] - cx[s], dy = f_y[f] - cy[s], dz = f_z[f] - cz[s];
                    if (dx * dx + dy * dy + dz * dz < 4.0f) { found = true; break; }
                }
            }
            if (found) sflag[s] = true;
            else pend[s] = true;
        }
        // single-shot cooperative resolve (loops only on overflow)
        do {
            if (tid == 0) cnt[1] = 0;
            __syncthreads();   // fences prior q_* reads vs rewrites
            int qe[SPT];
            #pragma unroll
            for (int s = 0; s < SPT; ++s) {
                qe[s] = -1;
                if (pend[s]) {
                    int e = atomicAdd(&cnt[1], 1);
                    if (e < MAXQ) {
                        q_key[e] = key[s]; q_x[e] = cx[s]; q_y[e] = cy[s]; q_z[e] = cz[s];
                        q_res[e] = 0;
                        qe[s] = e; pend[s] = false;
                    }
                }
            }
            __syncthreads();
            const int Q = min(cnt[1], MAXQ);
            for (int e = 0; e < Q; ++e) {     // uniform loop
                unsigned long long qk = q_key[e];
                float qx = q_x[e], qy = q_y[e], qz = q_z[e];
                bool hit = false;
                #pragma unroll
                for (int s = 0; s < SPT; ++s) {
                    if (act[s] && key[s] < qk) {
                        float dx = cx[s] - qx, dy = cy[s] - qy, dz = cz[s] - qz;
                        if (dx * dx + dy * dy + dz * dz < 4.0f) hit = true;
                    }
                }
                if (hit) q_res[e] = 1;        // benign race: all writers store 1
            }
            __syncthreads();
            #pragma unroll
            for (int s = 0; s < SPT; ++s)
                if (qe[s] >= 0) sflag[s] = (q_res[qe[s]] != 0);
        } while (cnt[1] > MAXQ);

        // pass 2: supp[j] = exists u in U={active,!s} with key_u<key_j, d<cutoff
        bool upend[SPT], supp[SPT];
        #pragma unroll
        for (int s = 0; s < SPT; ++s) {
            upend[s] = act[s] && !sflag[s];
            supp[s] = false;
        }
        do {
            if (tid == 0) cnt[2] = 0;
            __syncthreads();   // fences prior u_* reads vs rewrites
            #pragma unroll
            for (int s = 0; s < SPT; ++s) {
                if (upend[s]) {
                    int e = atomicAdd(&cnt[2], 1);
                    if (e < MAXU) {
                        u_key[e] = key[s]; u_x[e] = cx[s]; u_y[e] = cy[s]; u_z[e] = cz[s];
                        upend[s] = false;
                    }
                }
            }
            __syncthreads();
            const int Ku = min(cnt[2], MAXU);
            #pragma unroll
            for (int s = 0; s < SPT; ++s) {
                if (!act[s] || supp[s]) continue;
                for (int e = 0; e < Ku; ++e) {
                    if (u_key[e] < key[s]) {
                        float dx = u_x[e] - cx[s], dy = u_y[e] - cy[s], dz = u_z[e] - cz[s];
                        if (dx * dx + dy * dy + dz * dz < 4.0f) { supp[s] = true; break; }
                    }
                }
            }
        } while (cnt[2] > MAXU);
        // commit
        int loc = 0;
        #pragma unroll
        for (int s = 0; s < SPT; ++s) {
            if (act[s] && supp[s]) act[s] = false;
            loc += act[s] ? 1 : 0;
        }
        prev = cur;
        cur = blockReduceSumI(loc, scr_i, tid);
    }
    const int n_pd = cur;

    // ---- matching: kept preds vs all targets, lowest target idx wins ----
    bool kpend[SPT];
    #pragma unroll
    for (int s = 0; s < SPT; ++s) kpend[s] = act[s];
    int loc_tp = 0;
    float loc_ang = 0.0f;
    do {
        if (tid == 0) cnt[3] = 0;
        __syncthreads();   // fences prior k_* reads vs rewrites
        #pragma unroll
        for (int s = 0; s < SPT; ++s) {
            if (kpend[s]) {
                int e = atomicAdd(&cnt[3], 1);
                if (e < MAXK) {
                    k_x[e] = cx[s] * 25.0f; k_y[e] = cy[s] * 25.0f; k_z[e] = cz[s] * 4.0f;
                    k_idx[e] = pidx[s];
                    k_match[e] = 0xFFFFFFFFu;
                    kpend[s] = false;
                }
            }
        }
        __syncthreads();
        const int K = min(cnt[3], MAXK);
        #pragma unroll
        for (int s = 0; s < SPT; ++s) {
            if (!t_act[s]) continue;
            float tx = t_x[s], ty = t_y[s], tz = t_z[s];
            for (int e = 0; e < K; ++e) {
                float dx = tx - k_x[e], dy = ty - k_y[e], dz = tz - k_z[e];
                if (dx * dx + dy * dy + dz * dz < 4.0f)
                    atomicMin(&k_match[e], (unsigned int)t_n[s]);  // few hits
            }
        }
        __syncthreads();
        if (tid < K) {
            unsigned int m = k_match[tid];
            if (m != 0xFFFFFFFFu) {
                ++loc_tp;
                const float2* pr = (const float2*)(pb + (size_t)k_idx[tid] * 10 + 4);
                float2 p0 = pr[0], p1 = pr[1], p2v = pr[2];
                float ax0 = p0.x, ax1 = p0.y, ax2 = p1.x;
                float ay0 = p1.y, ay1 = p2v.x, ay2 = p2v.y;
                float az0 = ax1 * ay2 - ax2 * ay1;
                float az1 = ax2 * ay0 - ax0 * ay2;
                float az2 = ax0 * ay1 - ax1 * ay0;
                const float2* tr = (const float2*)(tb + (size_t)m * 10 + 4);
                float2 t0 = tr[0], t1 = tr[1], t2v = tr[2];
                float bx0 = t0.x, bx1 = t0.y, bx2 = t1.x;
                float by0 = t1.y, by1 = t2v.x, by2 = t2v.y;
                float bz0 = bx1 * by2 - bx2 * by1;
                float bz1 = bx2 * by0 - bx0 * by2;
                float bz2 = bx0 * by1 - bx1 * by0;
                loc_ang += rowAngleDeg(ax0, ax1, ax2, bx0, bx1, bx2);
                loc_ang += rowAngleDeg(ay0, ay1, ay2, by0, by1, by2);
                loc_ang += rowAngleDeg(az0, az1, az2, bz0, bz1, bz2);
            }
        }
    } while (cnt[3] > MAXK);

    // ---- fused epilogue reduction: tp (int) + angsum (float), one barrier ----
    #pragma unroll
    for (int o = 32; o > 0; o >>= 1) {
        loc_tp  += __shfl_down(loc_tp,  o, 64);
        loc_ang += __shfl_down(loc_ang, o, 64);
    }
    if ((tid & 63) == 0) { scr_i[tid >> 6] = loc_tp; scr_f[tid >> 6] = loc_ang; }
    __syncthreads();
    if (tid == 0) {
        int tp = 0; float angsum = 0.0f;
        #pragma unroll
        for (int w = 0; w < NWAVE; ++w) { tp += scr_i[w]; angsum += scr_f[w]; }
        out[b * 3 + 0] = (float)tp;
        out[b * 3 + 1] = (float)(n_pd - tp);
        out[b * 3 + 2] = (float)(nt - tp);
        out[NB * 3 + b] = (tp > 0) ? (angsum / (3.0f * (float)tp)) : 0.0f;
    }
}

extern "C" void kernel_launch(void* const* d_in, const int* in_sizes, int n_in,
                              void* d_out, int out_size, void* d_ws, size_t ws_size,
                              hipStream_t stream) {
    const float* pred = (const float*)d_in[0];
    const float* targ = (const float*)d_in[1];
    float* out = (float*)d_out;
    unsigned char* ws = (unsigned char*)d_ws;
    prep_kernel<<<dim3(256), dim3(256), 0, stream>>>(pred, targ, ws);
    molan_kernel<<<dim3(NB), dim3(NTH), 0, stream>>>(pred, targ, ws, out);
}

// Round 12
// 76.760 us; speedup vs baseline: 1.5315x; 1.0496x over previous
//
#include <hip/hip_runtime.h>
#include <math.h>

#define NB    8
#define NPTS  4096
#define NTH   1024        // 16 waves/CU -> max latency hiding for this shape
#define SPT   4
#define NWAVE (NTH / 64)
#define NFILT 16
#define MAXQ  512
#define MAXU  256
#define MAXK  256

// d_ws layout (~1.3 MB; no initialization required)
#define WS_PCC  0         // u32[8][16] pred active count per 256-chunk
#define WS_TCC  512       // u32[8][16] targ active count per 256-chunk
#define WS_PKEY 1024      // u64[8][4096] pred keys (chunk-local compaction)
#define WS_PPOS 263168    // float4[8][4096] pred pos (normalized) + idx in .w
#define WS_TPOS 787456    // float4[8][4096] targ pos (real) + idx in .w

__device__ __forceinline__ int blockReduceSumI(int v, int* scr, int tid) {
    #pragma unroll
    for (int o = 32; o > 0; o >>= 1) v += __shfl_down(v, o, 64);
    if ((tid & 63) == 0) scr[tid >> 6] = v;
    __syncthreads();
    if (tid == 0) {
        int s = 0;
        #pragma unroll
        for (int w = 0; w < NWAVE; ++w) s += scr[w];
        scr[16] = s;
    }
    __syncthreads();
    return scr[16];
}

__device__ __forceinline__ float rowAngleDeg(float a0, float a1, float a2,
                                             float b0, float b1, float b2) {
    float dot = a0 * b0 + a1 * b1 + a2 * b2;
    float na = sqrtf(a0 * a0 + a1 * a1 + a2 * a2);
    float nb = sqrtf(b0 * b0 + b1 * b1 + b2 * b2);
    float c = dot / (na * nb);
    c = fminf(1.0f, fmaxf(-1.0f, c));
    return acosf(c) * 57.29577951308232f;  // /pi*180
}

// Prep: full-chip parallel load + chunk-local compaction. 256 blocks x 256.
// Zero global atomics; each block owns one (tensor,batch,chunk) and writes
// its count with a plain store (no counter init needed).
__global__ __launch_bounds__(256) void prep_kernel(const float* __restrict__ pred,
                                                   const float* __restrict__ targ,
                                                   unsigned char* __restrict__ ws) {
    __shared__ int wcnt[4];
    unsigned int* pcc = (unsigned int*)(ws + WS_PCC);
    unsigned int* tcc = (unsigned int*)(ws + WS_TCC);
    unsigned long long* pkey = (unsigned long long*)(ws + WS_PKEY);
    float4* ppos = (float4*)(ws + WS_PPOS);
    float4* tpos = (float4*)(ws + WS_TPOS);

    const int tid = threadIdx.x;
    const int blk = blockIdx.x;
    const int tensor = blk >> 7;            // 0 = pred, 1 = targ
    const int batch = (blk >> 4) & 7;
    const int chunk = blk & 15;
    const int n = chunk * 256 + tid;
    const float* base = (tensor ? targ : pred)
                        + (size_t)batch * NPTS * 10 + (size_t)n * 10;
    float2 f0 = *(const float2*)base;         // conf_raw, off_z
    float2 f1 = *(const float2*)(base + 2);   // off_x, off_y
    float gz = (float)(n >> 10);
    float gx = (float)((n >> 5) & 31);
    float gy = (float)(n & 31);

    bool active;
    unsigned long long key = 0;
    float4 rec;
    if (tensor == 0) {
        float conf = 1.0f / (1.0f + expf(-f0.x));   // jax.nn.sigmoid
        active = conf > 0.5f;
        unsigned int u = ~(__float_as_uint(conf) | 0x80000000u);  // conf desc
        key = ((unsigned long long)u << 32) | (unsigned int)n;    // idx asc
        rec = make_float4((f0.y + gz) * 0.25f,
                          (f1.x + gx) * 0.03125f,
                          (f1.y + gy) * 0.03125f,
                          (float)n);
    } else {
        active = f0.x > 0.5f;
        rec = make_float4((f0.y + gz) * 0.25f * 25.0f,
                          (f1.x + gx) * 0.03125f * 25.0f,
                          (f1.y + gy) * 0.03125f * 4.0f,
                          (float)n);
    }

    const int lane = tid & 63, wid = tid >> 6;
    unsigned long long ball = __ballot(active);
    int lofs = __popcll(ball & ((1ull << lane) - 1ull));
    if (lane == 0) wcnt[wid] = __popcll(ball);
    __syncthreads();
    int wb = 0;
    for (int w = 0; w < wid; ++w) wb += wcnt[w];
    if (tid == 0) {
        unsigned int t = (unsigned int)(wcnt[0] + wcnt[1] + wcnt[2] + wcnt[3]);
        (tensor ? tcc : pcc)[batch * 16 + chunk] = t;
    }
    if (active) {
        int e = batch * NPTS + chunk * 256 + wb + lofs;
        if (tensor == 0) { pkey[e] = key; ppos[e] = rec; }
        else tpos[e] = rec;
    }
}

// Main: one block per batch (1024 thr), compacted records only. Sort-free NMS
// (order via u64 keys); single-shot chunk loops with overflow fallback;
// benign-race LDS result stores; prefetched packed-queue resolve.
__global__ __launch_bounds__(NTH) void molan_kernel(const float* __restrict__ pred,
                                                    const float* __restrict__ targ,
                                                    const unsigned char* __restrict__ ws,
                                                    float* __restrict__ out) {
    __shared__ int   scr_i[32];
    __shared__ float scr_f[32];
    __shared__ int   cnt[4];
    __shared__ int   ccP[16], ccT[16];
    __shared__ unsigned long long f_key[NFILT];
    __shared__ float f_x[NFILT], f_y[NFILT], f_z[NFILT];
    __shared__ ulonglong2 q_a[MAXQ];          // (key, packed xy) -> one b128
    __shared__ float q_z[MAXQ];
    __shared__ int   q_res[MAXQ];
    __shared__ unsigned long long u_key[MAXU];
    __shared__ float u_x[MAXU], u_y[MAXU], u_z[MAXU];
    __shared__ float k_x[MAXK], k_y[MAXK], k_z[MAXK];
    __shared__ int   k_idx[MAXK];
    __shared__ unsigned int k_match[MAXK];

    const int b = blockIdx.x;
    const int tid = threadIdx.x;
    const float* pb = pred + (size_t)b * NPTS * 10;
    const float* tb = targ + (size_t)b * NPTS * 10;
    const unsigned long long* pkey = (const unsigned long long*)(ws + WS_PKEY) + b * NPTS;
    const float4* ppos = (const float4*)(ws + WS_PPOS) + b * NPTS;
    const float4* tpos = (const float4*)(ws + WS_TPOS) + b * NPTS;

    if (tid < 16) ccP[tid] = (int)((const unsigned int*)(ws + WS_PCC))[b * 16 + tid];
    else if (tid < 32) ccT[tid - 16] = (int)((const unsigned int*)(ws + WS_TCC))[b * 16 + tid - 16];
    __syncthreads();
    int np = 0, nt = 0;
    #pragma unroll
    for (int i = 0; i < 16; ++i) { np += ccP[i]; nt += ccT[i]; }

    // ---- load compacted records into registers (chunk-local gating) ----
    unsigned long long key[SPT];
    bool  act[SPT];
    int   pidx[SPT];
    float cx[SPT], cy[SPT], cz[SPT];
    #pragma unroll
    for (int s = 0; s < SPT; ++s) {
        int slot = tid + NTH * s;
        bool a = (slot & 255) < ccP[slot >> 8];
        act[s] = a;
        key[s] = ~0ull;
        cx[s] = cy[s] = cz[s] = 0.f; pidx[s] = 0;
        if (a) {
            key[s] = pkey[slot];
            float4 p = ppos[slot];
            cx[s] = p.x; cy[s] = p.y; cz[s] = p.z; pidx[s] = (int)p.w;
        }
    }
    bool  t_act[SPT];
    int   t_n[SPT];
    float t_x[SPT], t_y[SPT], t_z[SPT];
    #pragma unroll
    for (int s = 0; s < SPT; ++s) {
        int slot = tid + NTH * s;
        bool a = (slot & 255) < ccT[slot >> 8];
        t_act[s] = a;
        t_x[s] = t_y[s] = t_z[s] = 0.f; t_n[s] = 0;
        if (a) {
            float4 p = tpos[slot];
            t_x[s] = p.x; t_y[s] = p.y; t_z[s] = p.z; t_n[s] = (int)p.w;
        }
    }

    // ---- NMS fixpoint (exact reference trajectory, order via keys) ----
    int cur = np;
    int prev = -1;
    while (cur != prev) {
        // filter = per-wave confidence champion (min key among actives)
        {
            unsigned long long bk = ~0ull;
            float bx = 0.f, by = 0.f, bz = 0.f;
            #pragma unroll
            for (int s = 0; s < SPT; ++s)
                if (act[s] && key[s] < bk) { bk = key[s]; bx = cx[s]; by = cy[s]; bz = cz[s]; }
            #pragma unroll
            for (int o = 32; o > 0; o >>= 1) {
                unsigned long long ok = __shfl_xor(bk, o, 64);
                float ox = __shfl_xor(bx, o, 64);
                float oy = __shfl_xor(by, o, 64);
                float oz = __shfl_xor(bz, o, 64);
                if (ok < bk) { bk = ok; bx = ox; by = oy; bz = oz; }
            }
            if ((tid & 63) == 0) {
                int w = tid >> 6;
                f_key[w] = bk; f_x[w] = bx; f_y[w] = by; f_z[w] = bz;
            }
        }
        __syncthreads();

        // pass 1: s[j] = exists active i (key_i<key_j) within cutoff
        bool sflag[SPT], pend[SPT];
        #pragma unroll
        for (int s = 0; s < SPT; ++s) {
            sflag[s] = false; pend[s] = false;
            if (!act[s]) continue;
            bool found = false;
            for (int f = 0; f < NFILT; ++f) {
                if (f_key[f] < key[s]) {
                    float dx = f_x[f] - cx[s], dy = f_y[f] - cy[s], dz = f_z[f] - cz[s];
                    if (dx * dx + dy * dy + dz * dz < 4.0f) { found = true; break; }
                }
            }
            if (found) sflag[s] = true;
            else pend[s] = true;
        }
        // single-shot cooperative resolve (loops only on overflow)
        do {
            if (tid == 0) cnt[1] = 0;
            __syncthreads();   // fences prior q_* reads vs rewrites
            int qe[SPT];
            #pragma unroll
            for (int s = 0; s < SPT; ++s) {
                qe[s] = -1;
                if (pend[s]) {
                    int e = atomicAdd(&cnt[1], 1);
                    if (e < MAXQ) {
                        unsigned long long xy =
                            ((unsigned long long)__float_as_uint(cy[s]) << 32)
                            | __float_as_uint(cx[s]);
                        q_a[e] = make_ulonglong2(key[s], xy);
                        q_z[e] = cz[s];
                        q_res[e] = 0;
                        qe[s] = e; pend[s] = false;
                    }
                }
            }
            __syncthreads();
            const int Q = min(cnt[1], MAXQ);
            if (Q > 0) {
                ulonglong2 a = q_a[0];
                float zz = q_z[0];
                for (int e = 0; e < Q; ++e) {   // uniform loop, prefetch e+1
                    ulonglong2 an = a; float zn = zz;
                    if (e + 1 < Q) { an = q_a[e + 1]; zn = q_z[e + 1]; }
                    unsigned long long qk = a.x;
                    float qx = __uint_as_float((unsigned int)a.y);
                    float qy = __uint_as_float((unsigned int)(a.y >> 32));
                    float qz = zz;
                    bool hit = false;
                    #pragma unroll
                    for (int s = 0; s < SPT; ++s) {
                        if (act[s] && key[s] < qk) {
                            float dx = cx[s] - qx, dy = cy[s] - qy, dz = cz[s] - qz;
                            if (dx * dx + dy * dy + dz * dz < 4.0f) hit = true;
                        }
                    }
                    if (hit) q_res[e] = 1;      // benign race: all store 1
                    a = an; zz = zn;
                }
            }
            __syncthreads();
            #pragma unroll
            for (int s = 0; s < SPT; ++s)
                if (qe[s] >= 0) sflag[s] = (q_res[qe[s]] != 0);
        } while (cnt[1] > MAXQ);

        // pass 2: supp[j] = exists u in U={active,!s} with key_u<key_j, d<cutoff
        bool upend[SPT], supp[SPT];
        #pragma unroll
        for (int s = 0; s < SPT; ++s) {
            upend[s] = act[s] && !sflag[s];
            supp[s] = false;
        }
        do {
            if (tid == 0) cnt[2] = 0;
            __syncthreads();   // fences prior u_* reads vs rewrites
            #pragma unroll
            for (int s = 0; s < SPT; ++s) {
                if (upend[s]) {
                    int e = atomicAdd(&cnt[2], 1);
                    if (e < MAXU) {
                        u_key[e] = key[s]; u_x[e] = cx[s]; u_y[e] = cy[s]; u_z[e] = cz[s];
                        upend[s] = false;
                    }
                }
            }
            __syncthreads();
            const int Ku = min(cnt[2], MAXU);
            #pragma unroll
            for (int s = 0; s < SPT; ++s) {
                if (!act[s] || supp[s]) continue;
                for (int e = 0; e < Ku; ++e) {
                    if (u_key[e] < key[s]) {
                        float dx = u_x[e] - cx[s], dy = u_y[e] - cy[s], dz = u_z[e] - cz[s];
                        if (dx * dx + dy * dy + dz * dz < 4.0f) { supp[s] = true; break; }
                    }
                }
            }
        } while (cnt[2] > MAXU);
        // commit
        int loc = 0;
        #pragma unroll
        for (int s = 0; s < SPT; ++s) {
            if (act[s] && supp[s]) act[s] = false;
            loc += act[s] ? 1 : 0;
        }
        prev = cur;
        cur = blockReduceSumI(loc, scr_i, tid);
    }
    const int n_pd = cur;

    // ---- matching: kept preds vs all targets, lowest target idx wins ----
    bool kpend[SPT];
    #pragma unroll
    for (int s = 0; s < SPT; ++s) kpend[s] = act[s];
    int loc_tp = 0;
    float loc_ang = 0.0f;
    do {
        if (tid == 0) cnt[3] = 0;
        __syncthreads();   // fences prior k_* reads vs rewrites
        #pragma unroll
        for (int s = 0; s < SPT; ++s) {
            if (kpend[s]) {
                int e = atomicAdd(&cnt[3], 1);
                if (e < MAXK) {
                    k_x[e] = cx[s] * 25.0f; k_y[e] = cy[s] * 25.0f; k_z[e] = cz[s] * 4.0f;
                    k_idx[e] = pidx[s];
                    k_match[e] = 0xFFFFFFFFu;
                    kpend[s] = false;
                }
            }
        }
        __syncthreads();
        const int K = min(cnt[3], MAXK);
        #pragma unroll
        for (int s = 0; s < SPT; ++s) {
            if (!t_act[s]) continue;
            float tx = t_x[s], ty = t_y[s], tz = t_z[s];
            for (int e = 0; e < K; ++e) {
                float dx = tx - k_x[e], dy = ty - k_y[e], dz = tz - k_z[e];
                if (dx * dx + dy * dy + dz * dz < 4.0f)
                    atomicMin(&k_match[e], (unsigned int)t_n[s]);  // few hits
            }
        }
        __syncthreads();
        if (tid < K) {
            unsigned int m = k_match[tid];
            if (m != 0xFFFFFFFFu) {
                ++loc_tp;
                const float2* pr = (const float2*)(pb + (size_t)k_idx[tid] * 10 + 4);
                float2 p0 = pr[0], p1 = pr[1], p2v = pr[2];
                float ax0 = p0.x, ax1 = p0.y, ax2 = p1.x;
                float ay0 = p1.y, ay1 = p2v.x, ay2 = p2v.y;
                float az0 = ax1 * ay2 - ax2 * ay1;
                float az1 = ax2 * ay0 - ax0 * ay2;
                float az2 = ax0 * ay1 - ax1 * ay0;
                const float2* tr = (const float2*)(tb + (size_t)m * 10 + 4);
                float2 t0 = tr[0], t1 = tr[1], t2v = tr[2];
                float bx0 = t0.x, bx1 = t0.y, bx2 = t1.x;
                float by0 = t1.y, by1 = t2v.x, by2 = t2v.y;
                float bz0 = bx1 * by2 - bx2 * by1;
                float bz1 = bx2 * by0 - bx0 * by2;
                float bz2 = bx0 * by1 - bx1 * by0;
                loc_ang += rowAngleDeg(ax0, ax1, ax2, bx0, bx1, bx2);
                loc_ang += rowAngleDeg(ay0, ay1, ay2, by0, by1, by2);
                loc_ang += rowAngleDeg(az0, az1, az2, bz0, bz1, bz2);
            }
        }
    } while (cnt[3] > MAXK);

    // ---- fused epilogue reduction: tp (int) + angsum (float), one barrier ----
    #pragma unroll
    for (int o = 32; o > 0; o >>= 1) {
        loc_tp  += __shfl_down(loc_tp,  o, 64);
        loc_ang += __shfl_down(loc_ang, o, 64);
    }
    if ((tid & 63) == 0) { scr_i[tid >> 6] = loc_tp; scr_f[tid >> 6] = loc_ang; }
    __syncthreads();
    if (tid == 0) {
        int tp = 0; float angsum = 0.0f;
        #pragma unroll
        for (int w = 0; w < NWAVE; ++w) { tp += scr_i[w]; angsum += scr_f[w]; }
        out[b * 3 + 0] = (float)tp;
        out[b * 3 + 1] = (float)(n_pd - tp);
        out[b * 3 + 2] = (float)(nt - tp);
        out[NB * 3 + b] = (tp > 0) ? (angsum / (3.0f * (float)tp)) : 0.0f;
    }
}

extern "C" void kernel_launch(void* const* d_in, const int* in_sizes, int n_in,
                              void* d_out, int out_size, void* d_ws, size_t ws_size,
                              hipStream_t stream) {
    const float* pred = (const float*)d_in[0];
    const float* targ = (const float*)d_in[1];
    float* out = (float*)d_out;
    unsigned char* ws = (unsigned char*)d_ws;
    prep_kernel<<<dim3(256), dim3(256), 0, stream>>>(pred, targ, ws);
    molan_kernel<<<dim3(NB), dim3(NTH), 0, stream>>>(pred, targ, ws, out);
}